// Round 6
// baseline (781.188 us; speedup 1.0000x reference)
//
#include <hip/hip_runtime.h>
#include <hip/hip_fp16.h>
#include <cstdint>
#include <cstddef>

// Problem constants (fixed by the reference file)
#define DIM    384
#define HEADS  6
#define HD     64
#define NTOK   15768
#define NMID   1728
#define BATCH  2
#define ROWS   (BATCH*NTOK)   // 31536
#define MPAD   31616          // 247*128  (GEMM row-tile padding)
#define L1START 13824         // 8*NMID
#define L2START 15552         // 9*NMID
#define HID    96
#define VROWS  (ROWS + 8)     // +pad row for x==Dl spill (weight 0)
#define VSLAB  ((size_t)VROWS * 64)   // per-head slab in __half elements

typedef __attribute__((ext_vector_type(8))) short short8;   // 8 bf16 (4 VGPRs)
typedef __attribute__((ext_vector_type(4))) float floatx4;  // MFMA accumulator

__device__ __forceinline__ unsigned short f2bf(float x){
  unsigned u = __float_as_uint(x);
  unsigned r = (u + 0x7FFFu + ((u >> 16) & 1u)) >> 16;   // round-to-nearest-even
  return (unsigned short)r;
}

__device__ __forceinline__ float wave_sum(float v){
  #pragma unroll
  for (int o = 32; o; o >>= 1) v += __shfl_xor(v, o, 64);
  return v;
}

// LayerNorm over 384 channels held as 6 regs/lane (c = j*64 + lane)
__device__ __forceinline__ void ln384(const float* x, float* y,
                                      const float* __restrict__ w,
                                      const float* __restrict__ b, int lane){
  float s = 0.f;
  #pragma unroll
  for (int j = 0; j < 6; j++) s += x[j];
  s = wave_sum(s);
  float m = s * (1.f/384.f);
  float v = 0.f;
  #pragma unroll
  for (int j = 0; j < 6; j++){ float d = x[j] - m; v += d*d; }
  v = wave_sum(v) * (1.f/384.f);
  float rs = rsqrtf(v + 1e-6f);
  #pragma unroll
  for (int j = 0; j < 6; j++){
    int c = j*64 + lane;
    y[j] = (x[j] - m) * rs * w[c] + b[c];
  }
}

// q = query (+feat on mid segment); qn=LN(q) fp32; aq=LN(qn) bf16; af=LN(LN(q,fnorm)) bf16
__global__ void k_ln_front(const float* __restrict__ query, const float* __restrict__ feat,
                           const float* __restrict__ qw,  const float* __restrict__ qb,
                           const float* __restrict__ fw,  const float* __restrict__ fb,
                           const float* __restrict__ eqw, const float* __restrict__ eqb,
                           const float* __restrict__ efw, const float* __restrict__ efb,
                           float* __restrict__ qn, unsigned short* __restrict__ aq,
                           unsigned short* __restrict__ af){
  int wid = blockIdx.x * (blockDim.x >> 6) + (threadIdx.x >> 6);
  if (wid >= ROWS) return;
  int lane = threadIdx.x & 63;
  int b = wid / NTOK, t = wid - b*NTOK;
  const float* qp = query + (size_t)wid * DIM;
  float x[6];
  #pragma unroll
  for (int j = 0; j < 6; j++) x[j] = qp[j*64 + lane];
  if (t >= L1START && t < L2START){
    const float* fp = feat + ((size_t)b*NMID + (t - L1START)) * DIM;
    #pragma unroll
    for (int j = 0; j < 6; j++) x[j] += fp[j*64 + lane];
  }
  float y[6], z[6];
  ln384(x, y, qw, qb, lane);                 // qn
  {
    float* o = qn + (size_t)wid * DIM;
    #pragma unroll
    for (int j = 0; j < 6; j++) o[j*64 + lane] = y[j];
  }
  ln384(y, z, eqw, eqb, lane);               // aq = LN(qn)
  {
    unsigned short* o = aq + (size_t)wid * DIM;
    #pragma unroll
    for (int j = 0; j < 6; j++) o[j*64 + lane] = f2bf(z[j]);
  }
  ln384(x, y, fw, fb, lane);                 // fn
  ln384(y, z, efw, efb, lane);               // af = LN(fn)
  {
    unsigned short* o = af + (size_t)wid * DIM;
    #pragma unroll
    for (int j = 0; j < 6; j++) o[j*64 + lane] = f2bf(z[j]);
  }
}

// plain LN: out_bf16 = LN(in_f32, w, b)
__global__ void k_ln(const float* __restrict__ in, const float* __restrict__ w,
                     const float* __restrict__ b, unsigned short* __restrict__ out){
  int wid = blockIdx.x * (blockDim.x >> 6) + (threadIdx.x >> 6);
  if (wid >= ROWS) return;
  int lane = threadIdx.x & 63;
  float x[6], y[6];
  const float* p = in + (size_t)wid * DIM;
  #pragma unroll
  for (int j = 0; j < 6; j++) x[j] = p[j*64 + lane];
  ln384(x, y, w, b, lane);
  unsigned short* o = out + (size_t)wid * DIM;
  #pragma unroll
  for (int j = 0; j < 6; j++) o[j*64 + lane] = f2bf(y[j]);
}

// One-shot weight convert+transpose for all GEMMs + combined off/aw bias.
__global__ void k_cvt_all(const float* __restrict__ val_w, const float* __restrict__ off_w,
                          const float* __restrict__ aw_w,  const float* __restrict__ out_w,
                          const float* __restrict__ fc1_w, const float* __restrict__ fc2_w,
                          const float* __restrict__ off_b, const float* __restrict__ aw_b,
                          unsigned short* __restrict__ wt_val, unsigned short* __restrict__ wt_offaw,
                          unsigned short* __restrict__ wt_out, unsigned short* __restrict__ wt_fc1,
                          unsigned short* __restrict__ wt_fc2, float* __restrict__ offaw_b){
  int id = blockIdx.x * blockDim.x + threadIdx.x;
  if (id < 147456){                                   // val: K=384, Npad=384
    int n = id / 384, k = id - n*384;
    wt_val[id] = f2bf(val_w[(size_t)k*384 + n]);
  } else if (id < 294912){                            // off(216)+aw(72@256): K=384, Npad=384
    int i = id - 147456;
    int n = i / 384, k = i - n*384;
    float v = 0.f;
    if (n < 216) v = off_w[(size_t)k*216 + n];
    else if (n >= 256 && n < 328) v = aw_w[(size_t)k*72 + (n-256)];
    wt_offaw[i] = f2bf(v);
  } else if (id < 442368){                            // out: K=384, Npad=384
    int i = id - 294912;
    int n = i / 384, k = i - n*384;
    wt_out[i] = f2bf(out_w[(size_t)k*384 + n]);
  } else if (id < 491520){                            // fc1: K=384, N=96, Npad=128
    int i = id - 442368;
    int n = i / 384, k = i - n*384;
    wt_fc1[i] = f2bf((n < 96) ? fc1_w[(size_t)k*96 + n] : 0.f);
  } else if (id < 528384){                            // fc2: K=96, Npad=384
    int i = id - 491520;
    int n = i / 96, k = i - n*96;
    wt_fc2[i] = f2bf(fc2_w[(size_t)k*384 + n]);
  } else if (id < 528768){                            // combined off/aw bias [384]
    int n = id - 528384;
    float v = 0.f;
    if (n < 216) v = off_b[n];
    else if (n >= 256 && n < 328) v = aw_b[n-256];
    offaw_b[n] = v;
  }
}

// bf16 MFMA GEMM: C[M,N] = A[Mpad,K]bf16 @ Wt[Npad,K]bf16^T + bias (+R).
// 128x128 tile, BK=32, 256 threads. Staging via global_load_lds width=16.
// OUTMODE: 0 = f32 row-major; 1 = bf16 row-major; 2 = f16 value-layout [head][row][64]
template<int OUTMODE>
__global__ __launch_bounds__(256) void k_gemm(
    const unsigned short* __restrict__ A,
    const unsigned short* __restrict__ Wt,
    const float* __restrict__ bias,
    const float* __restrict__ R,
    void* __restrict__ Cv,
    int M, int N, int K){
  __shared__ __align__(16) unsigned short As[128*32];
  __shared__ __align__(16) unsigned short Bs[128*32];
  int tid = threadIdx.x;
  int w = tid >> 6, lane = tid & 63;
  int m0 = blockIdx.y * 128, n0 = blockIdx.x * 128;
  int m_off = (w & 1) * 64, n_off = (w >> 1) * 64;

  floatx4 acc[4][4] = {};

  int sr = lane >> 2;          // row within 16-row staging chunk
  int sc = (lane & 3) * 8;     // bf16-element offset within row (16B granules)
  int lrow = lane & 15;        // MFMA row/col within 16
  int kq = (lane >> 4) * 8;    // k-offset of this lane's 8-element fragment

  for (int k0 = 0; k0 < K; k0 += 32){
    #pragma unroll
    for (int s = 0; s < 2; s++){
      int c = w * 2 + s;       // chunk 0..7 (16 rows each)
      const unsigned short* ga = A  + (size_t)(m0 + c*16 + sr) * K + k0 + sc;
      __builtin_amdgcn_global_load_lds(
          (const __attribute__((address_space(1))) void*)ga,
          (__attribute__((address_space(3))) void*)(As + c*512), 16, 0, 0);
      const unsigned short* gb = Wt + (size_t)(n0 + c*16 + sr) * K + k0 + sc;
      __builtin_amdgcn_global_load_lds(
          (const __attribute__((address_space(1))) void*)gb,
          (__attribute__((address_space(3))) void*)(Bs + c*512), 16, 0, 0);
    }
    __syncthreads();
    short8 afr[4], bfr[4];
    #pragma unroll
    for (int i = 0; i < 4; i++)
      afr[i] = *(const short8*)(As + (m_off + i*16 + lrow)*32 + kq);
    #pragma unroll
    for (int j = 0; j < 4; j++)
      bfr[j] = *(const short8*)(Bs + (n_off + j*16 + lrow)*32 + kq);
    #pragma unroll
    for (int i = 0; i < 4; i++)
      #pragma unroll
      for (int j = 0; j < 4; j++)
        acc[i][j] = __builtin_amdgcn_mfma_f32_16x16x32_bf16(afr[i], bfr[j], acc[i][j], 0, 0, 0);
    __syncthreads();
  }

  // epilogue: C/D layout col = lane&15, row = (lane>>4)*4 + reg
  int cn = n0 + n_off + lrow;
  int rbase = m0 + m_off + (lane >> 4) * 4;
  #pragma unroll
  for (int j = 0; j < 4; j++){
    int n = cn + j*16;
    if (n >= N) continue;
    float bj = bias[n];
    #pragma unroll
    for (int i = 0; i < 4; i++){
      int mb = rbase + i*16;
      #pragma unroll
      for (int r = 0; r < 4; r++){
        int m = mb + r;
        if (m < M){
          float v = acc[i][j][r] + bj;
          if (R) v += R[(size_t)m * N + n];
          if (OUTMODE == 0)      ((float*)Cv)[(size_t)m * N + n] = v;
          else if (OUTMODE == 1) ((unsigned short*)Cv)[(size_t)m * N + n] = f2bf(v);
          else { // f16 value layout: [head = n>>6][row = m][ch = n&63]
            ((__half*)Cv)[(size_t)(n >> 6) * VSLAB + (size_t)m * 64 + (n & 63)] =
                __float2half_rn(v);
          }
        }
      }
    }
  }
}

// Multi-scale deformable sampling v4: one block per (b,token) [XCD-swizzled], one wave
// per head. value f16 in [head][row][64]; the two x-corners of a trilinear pair are
// ADJACENT 128 B rows -> one dword load per lane = 2 corners x 2 ch.
// v4: scalar-pointer addressing (readlane row -> SGPR pointer; zero VALU addr math),
// 4 pair-loads batched before consumption (vmcnt(3..0)), wave-uniform level branch
// with compile-time divisors.
__global__ __launch_bounds__(384) void k_msdeform(const __half* __restrict__ vt,
                                                  const float* __restrict__ offaw,
                                                  unsigned short* __restrict__ msout){
  int bx = blockIdx.x;
  int r = (bx & 7) * (ROWS/8) + (bx >> 3);   // XCD-aware swizzle
  int head = threadIdx.x >> 6;
  int lane = threadIdx.x & 63;
  int b = (r >= NTOK) ? 1 : 0;
  int t = r - b * NTOK;

  // wave-uniform level branch; compile-time divisors -> magic-mul
  float refd, refy, refx;
  if (t < L1START){
    int i = t;
    int dd = i / 576; int rem = i - dd*576; int yy = rem / 24; int xx = rem - yy*24;
    refd = (dd + 0.5f) * (1.f/24.f); refy = (yy + 0.5f) * (1.f/24.f); refx = (xx + 0.5f) * (1.f/24.f);
  } else if (t < L2START){
    int i = t - L1START;
    int dd = i / 144; int rem = i - dd*144; int yy = rem / 12; int xx = rem - yy*12;
    refd = (dd + 0.5f) * (1.f/12.f); refy = (yy + 0.5f) * (1.f/12.f); refx = (xx + 0.5f) * (1.f/12.f);
  } else {
    int i = t - L2START;
    int dd = i / 36; int rem = i - dd*36; int yy = rem / 6; int xx = rem - yy*6;
    refd = (dd + 0.5f) * (1.f/6.f); refy = (yy + 0.5f) * (1.f/6.f); refx = (xx + 0.5f) * (1.f/6.f);
  }

  int j = lane;  // point index (j < 12 active)

  float logit = (j < 12) ? offaw[(size_t)r * 384 + 256 + head * 12 + j] : -1e30f;
  float mx = logit;
  mx = fmaxf(mx, __shfl_xor(mx, 1));
  mx = fmaxf(mx, __shfl_xor(mx, 2));
  mx = fmaxf(mx, __shfl_xor(mx, 4));
  mx = fmaxf(mx, __shfl_xor(mx, 8));
  float e = (j < 12) ? __expf(logit - mx) : 0.f;
  float s = e;
  s += __shfl_xor(s, 1);
  s += __shfl_xor(s, 2);
  s += __shfl_xor(s, 4);
  s += __shfl_xor(s, 8);
  float aww = e / s;

  // per-point descriptors: 4 (cz,cy) pairs, each = {row of x-lo corner, f16x2 (wlo,whi)}
  int rowk[4] = {0,0,0,0};
  int wgtk[4] = {0,0,0,0};

  if (j < 12){
    int l = j >> 2;
    int Dl  = (l == 0) ? 24 : ((l == 1) ? 12 : 6);
    int lst = (l == 0) ? 0  : ((l == 1) ? L1START : L2START);
    const float* op = offaw + (size_t)r * 384 + head * 36 + j * 3;
    float od = op[0], ox = op[1], oy = op[2];
    float fDl = (float)Dl;
    float pd = refd * fDl + od - 0.5f;
    float px = refx * fDl + ox - 0.5f;
    float py = refy * fDl + oy - 0.5f;
    float fld = floorf(pd), flx = floorf(px), fly = floorf(py);
    float fd = pd - fld, fx = px - flx, fy = py - fly;
    int d0 = (int)fld, x0 = (int)flx, y0 = (int)fly;
    float wz2[2] = {(1.f - fd) * aww, fd * aww};
    float wy2[2] = {1.f - fy, fy};
    // x-pair mapping: load rows (rs, rs+1); weights assigned per clamp case
    int rs = min(max(x0, 0), Dl - 1);
    float wlo_x = (rs == x0) ? (1.f - fx) : ((rs == x0 + 1) ? fx : 0.f);
    float whi_x = ((rs == x0) && (x0 + 1 < Dl)) ? fx : 0.f;
    int rowbase = b * NTOK + lst;
    #pragma unroll
    for (int p = 0; p < 4; p++){
      int cz = p >> 1, cy = p & 1;
      int di = d0 + cz, yi = y0 + cy;
      bool vzy = (di >= 0) & (di < Dl) & (yi >= 0) & (yi < Dl);
      float wp = vzy ? wz2[cz] * wy2[cy] : 0.f;
      int dc = min(max(di, 0), Dl - 1);
      int yc = min(max(yi, 0), Dl - 1);
      rowk[p] = rowbase + (dc * Dl + yc) * Dl + rs;
      __half2 wh = __floats2half2_rn(wp * wlo_x, wp * whi_x);
      wgtk[p] = *(int*)&wh;
    }
  }

  int head_u = __builtin_amdgcn_readfirstlane(head);
  const __half2* vh = (const __half2*)(vt + (size_t)head_u * VSLAB);
  unsigned laneHi = lane & 32;           // loop-invariant select

  __half2 hz; *(int*)&hz = 0;
  __half2 a0 = hz, a1 = hz, a2 = hz, a3 = hz;
  float fLo = 0.f, fHi = 0.f;

  #pragma unroll
  for (int seg = 0; seg < 3; seg++){
    #pragma unroll
    for (int q = 0; q < 4; q++){
      int jj = seg * 4 + q;
      // broadcast pair descriptors to SGPRs; build scalar row pointers
      const __half2* rp0; const __half2* rp1; const __half2* rp2; const __half2* rp3;
      int sw0, sw1, sw2, sw3;
      {
        int s0 = __builtin_amdgcn_readlane(rowk[0], jj);
        int s1 = __builtin_amdgcn_readlane(rowk[1], jj);
        int s2 = __builtin_amdgcn_readlane(rowk[2], jj);
        int s3 = __builtin_amdgcn_readlane(rowk[3], jj);
        sw0 = __builtin_amdgcn_readlane(wgtk[0], jj);
        sw1 = __builtin_amdgcn_readlane(wgtk[1], jj);
        sw2 = __builtin_amdgcn_readlane(wgtk[2], jj);
        sw3 = __builtin_amdgcn_readlane(wgtk[3], jj);
        rp0 = vh + ((unsigned)s0 << 5);
        rp1 = vh + ((unsigned)s1 << 5);
        rp2 = vh + ((unsigned)s2 << 5);
        rp3 = vh + ((unsigned)s3 << 5);
      }
      // batched loads (independent; 4 in flight)
      __half2 v0 = rp0[lane];
      __half2 v1 = rp1[lane];
      __half2 v2 = rp2[lane];
      __half2 v3 = rp3[lane];
      // weight select per half-wave + packed fma
      unsigned u0 = laneHi ? (((unsigned)sw0 & 0xFFFF0000u) | ((unsigned)sw0 >> 16))
                           : (((unsigned)sw0 & 0xFFFFu) * 0x00010001u);
      unsigned u1 = laneHi ? (((unsigned)sw1 & 0xFFFF0000u) | ((unsigned)sw1 >> 16))
                           : (((unsigned)sw1 & 0xFFFFu) * 0x00010001u);
      unsigned u2 = laneHi ? (((unsigned)sw2 & 0xFFFF0000u) | ((unsigned)sw2 >> 16))
                           : (((unsigned)sw2 & 0xFFFFu) * 0x00010001u);
      unsigned u3 = laneHi ? (((unsigned)sw3 & 0xFFFF0000u) | ((unsigned)sw3 >> 16))
                           : (((unsigned)sw3 & 0xFFFFu) * 0x00010001u);
      a0 = __hfma2(*(__half2*)&u0, v0, a0);
      a1 = __hfma2(*(__half2*)&u1, v1, a1);
      a2 = __hfma2(*(__half2*)&u2, v2, a2);
      a3 = __hfma2(*(__half2*)&u3, v3, a3);
    }
    float2 f0 = __half22float2(a0), f1 = __half22float2(a1);
    float2 f2 = __half22float2(a2), f3 = __half22float2(a3);
    fLo += (f0.x + f1.x) + (f2.x + f3.x);
    fHi += (f0.y + f1.y) + (f2.y + f3.y);
    a0 = a1 = a2 = a3 = hz;
  }

  // lanes i and i+32 hold the x-lo / x-hi halves of the same channel pair
  float sLo = fLo + __shfl_xor(fLo, 32);
  float sHi = fHi + __shfl_xor(fHi, 32);
  if (lane < 32){
    unsigned packed = ((unsigned)f2bf(sHi) << 16) | (unsigned)f2bf(sLo);
    *(unsigned*)(msout + (size_t)r * DIM + head * 64 + lane * 2) = packed;
  }
}

// depthwise 3x3x3 SAME conv per level segment + exact GELU; bf16 output (feeds fc2 GEMM)
__global__ void k_dwconv_gelu(const float* __restrict__ h, const float* __restrict__ dww,
                              const float* __restrict__ dwb, unsigned short* __restrict__ h2){
  int gid = blockIdx.x * blockDim.x + threadIdx.x;
  if (gid >= ROWS * HID) return;
  int c = gid % HID;
  int r = gid / HID;
  int b = r / NTOK, t = r - b*NTOK;
  int base, DL;
  if (t < L1START){ base = 0; DL = 24; }
  else if (t < L2START){ base = L1START; DL = 12; }
  else { base = L2START; DL = 6; }
  int i = t - base;
  int hw = DL * DL;
  int dd = i / hw; int rem = i - dd*hw; int yy = rem / DL; int xx = rem - yy*DL;
  float acc = 0.f;
  #pragma unroll
  for (int kz = 0; kz < 3; kz++){
    int nd = dd + kz - 1; if (nd < 0 || nd >= DL) continue;
    #pragma unroll
    for (int ky = 0; ky < 3; ky++){
      int ny = yy + ky - 1; if (ny < 0 || ny >= DL) continue;
      #pragma unroll
      for (int kx = 0; kx < 3; kx++){
        int nx = xx + kx - 1; if (nx < 0 || nx >= DL) continue;
        int nt = base + (nd * DL + ny) * DL + nx;
        acc += h[((size_t)(b*NTOK + nt)) * HID + c] * dww[((kz*3 + ky)*3 + kx) * HID + c];
      }
    }
  }
  acc += dwb[c];
  float g = 0.5f * acc * (1.f + erff(acc * 0.70710678118654752440f));
  h2[(size_t)r * HID + c] = f2bf(g);
}

extern "C" void kernel_launch(void* const* d_in, const int* in_sizes, int n_in,
                              void* d_out, int out_size, void* d_ws, size_t ws_size,
                              hipStream_t stream){
  const float* query = (const float*)d_in[0];
  const float* feat  = (const float*)d_in[2];
  const float* qnw = (const float*)d_in[8],  *qnb = (const float*)d_in[9];
  const float* fnw = (const float*)d_in[10], *fnb = (const float*)d_in[11];
  const float* eqw = (const float*)d_in[12], *eqb = (const float*)d_in[13];
  const float* efw = (const float*)d_in[14], *efb = (const float*)d_in[15];
  const float* ffw = (const float*)d_in[16], *ffb = (const float*)d_in[17];
  const float* off_w = (const float*)d_in[18], *off_b = (const float*)d_in[19];
  const float* aw_w  = (const float*)d_in[20], *aw_b  = (const float*)d_in[21];
  const float* val_w = (const float*)d_in[22], *val_b = (const float*)d_in[23];
  const float* out_w = (const float*)d_in[24], *out_b = (const float*)d_in[25];
  const float* fc1_w = (const float*)d_in[26], *fc1_b = (const float*)d_in[27];
  const float* dw_w  = (const float*)d_in[28], *dw_b  = (const float*)d_in[29];
  const float* fc2_w = (const float*)d_in[30], *fc2_b = (const float*)d_in[31];
  float* out = (float*)d_out;

  // workspace layout (~171 MB with lifetime-disjoint aliasing)
  char* p = (char*)d_ws;
  float* qn             = (float*)p;          p += (size_t)ROWS*384*4;  // qn; later h2
  unsigned short* aq    = (unsigned short*)p; p += (size_t)MPAD*384*2;  // aq -> t
  unsigned short* af    = (unsigned short*)p; p += (size_t)MPAD*384*2;  // af -> msout
  __half* value_t       = (__half*)p;         p += (size_t)HEADS*VSLAB*2; // value; later h
  float* offaw          = (float*)p;          p += (size_t)ROWS*384*4;  // off+aw; later y1
  unsigned short* wt_val   = (unsigned short*)p; p += (size_t)384*384*2;
  unsigned short* wt_offaw = (unsigned short*)p; p += (size_t)384*384*2;
  unsigned short* wt_out   = (unsigned short*)p; p += (size_t)384*384*2;
  unsigned short* wt_fc1   = (unsigned short*)p; p += (size_t)128*384*2;
  unsigned short* wt_fc2   = (unsigned short*)p; p += (size_t)384*96*2;
  float* offaw_b           = (float*)p;          p += (size_t)384*4;
  // aliases (lifetime-disjoint)
  unsigned short* t_buf  = aq;                    // MPAD*384 bf16
  unsigned short* msout  = af;                    // MPAD*384 bf16
  float* y1              = offaw;                 // ROWS*384 f32 (offaw dead post-msdeform)
  float* h_buf           = (float*)value_t;       // ROWS*96 f32 (value dead post-msdeform)
  unsigned short* h2_buf = (unsigned short*)qn;   // MPAD*96 bf16 (qn dead post-out-GEMM)

  k_cvt_all<<<(528768 + 255)/256, 256, 0, stream>>>(val_w, off_w, aw_w, out_w, fc1_w, fc2_w,
                                                    off_b, aw_b,
                                                    wt_val, wt_offaw, wt_out, wt_fc1, wt_fc2,
                                                    offaw_b);

  int lnBlocks = ROWS / 4;
  k_ln_front<<<lnBlocks, 256, 0, stream>>>(query, feat, qnw, qnb, fnw, fnb,
                                           eqw, eqb, efw, efb, qn, aq, af);

  dim3 gN384(3, MPAD/128), gN128(1, MPAD/128);

  // value (f16, [head][row][64]) = af @ val_w + val_b
  k_gemm<2><<<gN384, 256, 0, stream>>>(af, wt_val, val_b, nullptr, value_t, ROWS, 384, 384);
  // off(0:216) + aw logits(256:328) = aq @ [off_w|aw_w] + [off_b|aw_b]
  k_gemm<0><<<gN384, 256, 0, stream>>>(aq, wt_offaw, offaw_b, nullptr, offaw, ROWS, 384, 384);
  // deformable sampling -> msout (bf16; af dead)
  k_msdeform<<<ROWS, 384, 0, stream>>>(value_t, offaw, msout);
  // y1 = msout @ out_w + out_b + qn   (offaw dead)
  k_gemm<0><<<gN384, 256, 0, stream>>>(msout, wt_out, out_b, qn, y1, ROWS, 384, 384);
  // t = LN(y1, ffn_norm)  (aq dead)
  k_ln<<<lnBlocks, 256, 0, stream>>>(y1, ffw, ffb, t_buf);
  // h = t @ fc1_w + fc1_b   (value dead)
  k_gemm<0><<<gN128, 256, 0, stream>>>(t_buf, wt_fc1, fc1_b, nullptr, h_buf, ROWS, 96, 384);
  // h2 = gelu(dwconv(h))    (qn dead)
  k_dwconv_gelu<<<(ROWS * HID + 255)/256, 256, 0, stream>>>(h_buf, dw_w, dw_b, h2_buf);
  // out = h2 @ fc2_w + fc2_b + y1
  k_gemm<0><<<gN384, 256, 0, stream>>>(h2_buf, wt_fc2, fc2_b, y1, out, ROWS, 384, 96);
}

// Round 7
// 536.122 us; speedup vs baseline: 1.4571x; 1.4571x over previous
//
#include <hip/hip_runtime.h>
#include <hip/hip_fp16.h>
#include <cstdint>
#include <cstddef>

// Problem constants (fixed by the reference file)
#define DIM    384
#define HEADS  6
#define HD     64
#define NTOK   15768
#define NMID   1728
#define BATCH  2
#define ROWS   (BATCH*NTOK)   // 31536
#define MPAD   31616          // 247*128  (GEMM row-tile padding)
#define L1START 13824         // 8*NMID
#define L2START 15552         // 9*NMID
#define HID    96
#define VROWS  (ROWS + 8)     // +pad row for x==Dl spill (weight 0)
#define VSLAB  ((size_t)VROWS * 64)   // per-head slab in __half elements

typedef __attribute__((ext_vector_type(8))) short short8;   // 8 bf16 (4 VGPRs)
typedef __attribute__((ext_vector_type(4))) float floatx4;  // MFMA accumulator

__device__ __forceinline__ unsigned short f2bf(float x){
  unsigned u = __float_as_uint(x);
  unsigned r = (u + 0x7FFFu + ((u >> 16) & 1u)) >> 16;   // round-to-nearest-even
  return (unsigned short)r;
}

__device__ __forceinline__ float wave_sum(float v){
  #pragma unroll
  for (int o = 32; o; o >>= 1) v += __shfl_xor(v, o, 64);
  return v;
}

// LayerNorm over 384 channels held as 6 regs/lane (c = j*64 + lane)
__device__ __forceinline__ void ln384(const float* x, float* y,
                                      const float* __restrict__ w,
                                      const float* __restrict__ b, int lane){
  float s = 0.f;
  #pragma unroll
  for (int j = 0; j < 6; j++) s += x[j];
  s = wave_sum(s);
  float m = s * (1.f/384.f);
  float v = 0.f;
  #pragma unroll
  for (int j = 0; j < 6; j++){ float d = x[j] - m; v += d*d; }
  v = wave_sum(v) * (1.f/384.f);
  float rs = rsqrtf(v + 1e-6f);
  #pragma unroll
  for (int j = 0; j < 6; j++){
    int c = j*64 + lane;
    y[j] = (x[j] - m) * rs * w[c] + b[c];
  }
}

// q = query (+feat on mid segment); qn=LN(q) fp32; aq=LN(qn) bf16; af=LN(LN(q,fnorm)) bf16
__global__ void k_ln_front(const float* __restrict__ query, const float* __restrict__ feat,
                           const float* __restrict__ qw,  const float* __restrict__ qb,
                           const float* __restrict__ fw,  const float* __restrict__ fb,
                           const float* __restrict__ eqw, const float* __restrict__ eqb,
                           const float* __restrict__ efw, const float* __restrict__ efb,
                           float* __restrict__ qn, unsigned short* __restrict__ aq,
                           unsigned short* __restrict__ af){
  int wid = blockIdx.x * (blockDim.x >> 6) + (threadIdx.x >> 6);
  if (wid >= ROWS) return;
  int lane = threadIdx.x & 63;
  int b = wid / NTOK, t = wid - b*NTOK;
  const float* qp = query + (size_t)wid * DIM;
  float x[6];
  #pragma unroll
  for (int j = 0; j < 6; j++) x[j] = qp[j*64 + lane];
  if (t >= L1START && t < L2START){
    const float* fp = feat + ((size_t)b*NMID + (t - L1START)) * DIM;
    #pragma unroll
    for (int j = 0; j < 6; j++) x[j] += fp[j*64 + lane];
  }
  float y[6], z[6];
  ln384(x, y, qw, qb, lane);                 // qn
  {
    float* o = qn + (size_t)wid * DIM;
    #pragma unroll
    for (int j = 0; j < 6; j++) o[j*64 + lane] = y[j];
  }
  ln384(y, z, eqw, eqb, lane);               // aq = LN(qn)
  {
    unsigned short* o = aq + (size_t)wid * DIM;
    #pragma unroll
    for (int j = 0; j < 6; j++) o[j*64 + lane] = f2bf(z[j]);
  }
  ln384(x, y, fw, fb, lane);                 // fn
  ln384(y, z, efw, efb, lane);               // af = LN(fn)
  {
    unsigned short* o = af + (size_t)wid * DIM;
    #pragma unroll
    for (int j = 0; j < 6; j++) o[j*64 + lane] = f2bf(z[j]);
  }
}

// plain LN: out_bf16 = LN(in_f32, w, b)
__global__ void k_ln(const float* __restrict__ in, const float* __restrict__ w,
                     const float* __restrict__ b, unsigned short* __restrict__ out){
  int wid = blockIdx.x * (blockDim.x >> 6) + (threadIdx.x >> 6);
  if (wid >= ROWS) return;
  int lane = threadIdx.x & 63;
  float x[6], y[6];
  const float* p = in + (size_t)wid * DIM;
  #pragma unroll
  for (int j = 0; j < 6; j++) x[j] = p[j*64 + lane];
  ln384(x, y, w, b, lane);
  unsigned short* o = out + (size_t)wid * DIM;
  #pragma unroll
  for (int j = 0; j < 6; j++) o[j*64 + lane] = f2bf(y[j]);
}

// One-shot weight convert+transpose for all GEMMs + combined off/aw bias.
__global__ void k_cvt_all(const float* __restrict__ val_w, const float* __restrict__ off_w,
                          const float* __restrict__ aw_w,  const float* __restrict__ out_w,
                          const float* __restrict__ fc1_w, const float* __restrict__ fc2_w,
                          const float* __restrict__ off_b, const float* __restrict__ aw_b,
                          unsigned short* __restrict__ wt_val, unsigned short* __restrict__ wt_offaw,
                          unsigned short* __restrict__ wt_out, unsigned short* __restrict__ wt_fc1,
                          unsigned short* __restrict__ wt_fc2, float* __restrict__ offaw_b){
  int id = blockIdx.x * blockDim.x + threadIdx.x;
  if (id < 147456){                                   // val: K=384, Npad=384
    int n = id / 384, k = id - n*384;
    wt_val[id] = f2bf(val_w[(size_t)k*384 + n]);
  } else if (id < 294912){                            // off(216)+aw(72@256): K=384, Npad=384
    int i = id - 147456;
    int n = i / 384, k = i - n*384;
    float v = 0.f;
    if (n < 216) v = off_w[(size_t)k*216 + n];
    else if (n >= 256 && n < 328) v = aw_w[(size_t)k*72 + (n-256)];
    wt_offaw[i] = f2bf(v);
  } else if (id < 442368){                            // out: K=384, Npad=384
    int i = id - 294912;
    int n = i / 384, k = i - n*384;
    wt_out[i] = f2bf(out_w[(size_t)k*384 + n]);
  } else if (id < 491520){                            // fc1: K=384, N=96, Npad=128
    int i = id - 442368;
    int n = i / 384, k = i - n*384;
    wt_fc1[i] = f2bf((n < 96) ? fc1_w[(size_t)k*96 + n] : 0.f);
  } else if (id < 528384){                            // fc2: K=96, Npad=384
    int i = id - 491520;
    int n = i / 96, k = i - n*96;
    wt_fc2[i] = f2bf(fc2_w[(size_t)k*384 + n]);
  } else if (id < 528768){                            // combined off/aw bias [384]
    int n = id - 528384;
    float v = 0.f;
    if (n < 216) v = off_b[n];
    else if (n >= 256 && n < 328) v = aw_b[n-256];
    offaw_b[n] = v;
  }
}

// bf16 MFMA GEMM: C[M,N] = A[Mpad,K]bf16 @ Wt[Npad,K]bf16^T + bias (+R).
// 128x128 tile, BK=32, 256 threads. Staging via global_load_lds width=16.
// OUTMODE: 0 = f32 row-major; 1 = bf16 row-major; 2 = f16 value-layout [head][row][64]
template<int OUTMODE>
__global__ __launch_bounds__(256) void k_gemm(
    const unsigned short* __restrict__ A,
    const unsigned short* __restrict__ Wt,
    const float* __restrict__ bias,
    const float* __restrict__ R,
    void* __restrict__ Cv,
    int M, int N, int K){
  __shared__ __align__(16) unsigned short As[128*32];
  __shared__ __align__(16) unsigned short Bs[128*32];
  int tid = threadIdx.x;
  int w = tid >> 6, lane = tid & 63;
  int m0 = blockIdx.y * 128, n0 = blockIdx.x * 128;
  int m_off = (w & 1) * 64, n_off = (w >> 1) * 64;

  floatx4 acc[4][4] = {};

  int sr = lane >> 2;          // row within 16-row staging chunk
  int sc = (lane & 3) * 8;     // bf16-element offset within row (16B granules)
  int lrow = lane & 15;        // MFMA row/col within 16
  int kq = (lane >> 4) * 8;    // k-offset of this lane's 8-element fragment

  for (int k0 = 0; k0 < K; k0 += 32){
    #pragma unroll
    for (int s = 0; s < 2; s++){
      int c = w * 2 + s;       // chunk 0..7 (16 rows each)
      const unsigned short* ga = A  + (size_t)(m0 + c*16 + sr) * K + k0 + sc;
      __builtin_amdgcn_global_load_lds(
          (const __attribute__((address_space(1))) void*)ga,
          (__attribute__((address_space(3))) void*)(As + c*512), 16, 0, 0);
      const unsigned short* gb = Wt + (size_t)(n0 + c*16 + sr) * K + k0 + sc;
      __builtin_amdgcn_global_load_lds(
          (const __attribute__((address_space(1))) void*)gb,
          (__attribute__((address_space(3))) void*)(Bs + c*512), 16, 0, 0);
    }
    __syncthreads();
    short8 afr[4], bfr[4];
    #pragma unroll
    for (int i = 0; i < 4; i++)
      afr[i] = *(const short8*)(As + (m_off + i*16 + lrow)*32 + kq);
    #pragma unroll
    for (int j = 0; j < 4; j++)
      bfr[j] = *(const short8*)(Bs + (n_off + j*16 + lrow)*32 + kq);
    #pragma unroll
    for (int i = 0; i < 4; i++)
      #pragma unroll
      for (int j = 0; j < 4; j++)
        acc[i][j] = __builtin_amdgcn_mfma_f32_16x16x32_bf16(afr[i], bfr[j], acc[i][j], 0, 0, 0);
    __syncthreads();
  }

  // epilogue: C/D layout col = lane&15, row = (lane>>4)*4 + reg
  int cn = n0 + n_off + lrow;
  int rbase = m0 + m_off + (lane >> 4) * 4;
  #pragma unroll
  for (int j = 0; j < 4; j++){
    int n = cn + j*16;
    if (n >= N) continue;
    float bj = bias[n];
    #pragma unroll
    for (int i = 0; i < 4; i++){
      int mb = rbase + i*16;
      #pragma unroll
      for (int r = 0; r < 4; r++){
        int m = mb + r;
        if (m < M){
          float v = acc[i][j][r] + bj;
          if (R) v += R[(size_t)m * N + n];
          if (OUTMODE == 0)      ((float*)Cv)[(size_t)m * N + n] = v;
          else if (OUTMODE == 1) ((unsigned short*)Cv)[(size_t)m * N + n] = f2bf(v);
          else { // f16 value layout: [head = n>>6][row = m][ch = n&63]
            ((__half*)Cv)[(size_t)(n >> 6) * VSLAB + (size_t)m * 64 + (n & 63)] =
                __float2half_rn(v);
          }
        }
      }
    }
  }
}

// Multi-scale deformable sampling v5: one block per (b,token) [XCD-swizzled], one wave
// per head. value f16 in [head][row][64]; x-corner pair = adjacent 128 B rows -> one
// dword load per lane = 2 corners x 2 ch (lanes 0-31 row x, 32-63 row x+1).
// v5 vs v4-regression: inner loop back to round-5 vector-addressed form, with
// (a) 48-lane-parallel descriptor setup (lane k = point k>>2, pair k&3),
// (b) 32-bit saddr offsets (one v_lshl_add_u32/pair), (c) v_perm weight select.
__global__ __launch_bounds__(384) void k_msdeform(const __half* __restrict__ vt,
                                                  const float* __restrict__ offaw,
                                                  unsigned short* __restrict__ msout){
  int bx = blockIdx.x;
  int r = (bx & 7) * (ROWS/8) + (bx >> 3);   // XCD-aware swizzle
  int head = threadIdx.x >> 6;
  int lane = threadIdx.x & 63;
  int b = (r >= NTOK) ? 1 : 0;
  int t = r - b * NTOK;

  // wave-uniform level branch; compile-time divisors -> magic-mul
  float refd, refy, refx;
  if (t < L1START){
    int i = t;
    int dd = i / 576; int rem = i - dd*576; int yy = rem / 24; int xx = rem - yy*24;
    refd = (dd + 0.5f) * (1.f/24.f); refy = (yy + 0.5f) * (1.f/24.f); refx = (xx + 0.5f) * (1.f/24.f);
  } else if (t < L2START){
    int i = t - L1START;
    int dd = i / 144; int rem = i - dd*144; int yy = rem / 12; int xx = rem - yy*12;
    refd = (dd + 0.5f) * (1.f/12.f); refy = (yy + 0.5f) * (1.f/12.f); refx = (xx + 0.5f) * (1.f/12.f);
  } else {
    int i = t - L2START;
    int dd = i / 36; int rem = i - dd*36; int yy = rem / 6; int xx = rem - yy*6;
    refd = (dd + 0.5f) * (1.f/6.f); refy = (yy + 0.5f) * (1.f/6.f); refx = (xx + 0.5f) * (1.f/6.f);
  }

  // softmax over the 12 (level,point) logits of this head (lanes 0-11, as round 5)
  float logit = (lane < 12) ? offaw[(size_t)r * 384 + 256 + head * 12 + lane] : -1e30f;
  float mx = logit;
  mx = fmaxf(mx, __shfl_xor(mx, 1));
  mx = fmaxf(mx, __shfl_xor(mx, 2));
  mx = fmaxf(mx, __shfl_xor(mx, 4));
  mx = fmaxf(mx, __shfl_xor(mx, 8));
  float e = (lane < 12) ? __expf(logit - mx) : 0.f;
  float s = e;
  s += __shfl_xor(s, 1);
  s += __shfl_xor(s, 2);
  s += __shfl_xor(s, 4);
  s += __shfl_xor(s, 8);
  float aww = e / s;
  // broadcast point weight to the 4 lanes handling that point's pairs
  float awwj = __shfl(aww, lane >> 2, 64);

  // per-lane pair descriptor: lane k<48 -> point j=k>>2, (cz,cy) pair p=k&3
  int rowk = 0, wgtk = 0;
  if (lane < 48){
    int j = lane >> 2, p = lane & 3;
    int l = j >> 2;
    int Dl  = (l == 0) ? 24 : ((l == 1) ? 12 : 6);
    int lst = (l == 0) ? 0  : ((l == 1) ? L1START : L2START);
    const float* op = offaw + (size_t)r * 384 + head * 36 + j * 3;
    float od = op[0], ox = op[1], oy = op[2];
    float fDl = (float)Dl;
    float pd = refd * fDl + od - 0.5f;
    float px = refx * fDl + ox - 0.5f;
    float py = refy * fDl + oy - 0.5f;
    float fld = floorf(pd), flx = floorf(px), fly = floorf(py);
    float fd = pd - fld, fx = px - flx, fy = py - fly;
    int d0 = (int)fld, x0 = (int)flx, y0 = (int)fly;
    int cz = p >> 1, cy = p & 1;
    int di = d0 + cz, yi = y0 + cy;
    bool vzy = (di >= 0) & (di < Dl) & (yi >= 0) & (yi < Dl);
    float wz = cz ? fd : 1.f - fd;
    float wy = cy ? fy : 1.f - fy;
    float wp = vzy ? (wz * awwj) * wy : 0.f;     // same order as r5: (wz*aww)*wy
    int rs = min(max(x0, 0), Dl - 1);
    float wlo_x = (rs == x0) ? (1.f - fx) : ((rs == x0 + 1) ? fx : 0.f);
    float whi_x = ((rs == x0) && (x0 + 1 < Dl)) ? fx : 0.f;
    int dc = min(max(di, 0), Dl - 1);
    int yc = min(max(yi, 0), Dl - 1);
    rowk = (b * NTOK + lst) + (dc * Dl + yc) * Dl + rs;    // < 32768
    __half2 wh = __floats2half2_rn(wp * wlo_x, wp * whi_x);
    wgtk = *(int*)&wh;
  }

  int head_u = __builtin_amdgcn_readfirstlane(head);
  const char* vbase = (const char*)(vt + (size_t)head_u * VSLAB);   // uniform SGPR base
  unsigned lane4 = (unsigned)lane << 2;
  // per-lane byte selector: lanes<32 dup lo16 of weight, lanes>=32 dup hi16
  unsigned selperm = (lane & 32) ? 0x03020302u : 0x01000100u;

  __half2 hz; *(int*)&hz = 0;
  __half2 a0 = hz, a1 = hz, a2 = hz, a3 = hz;
  float fLo = 0.f, fHi = 0.f;

  #pragma unroll
  for (int seg = 0; seg < 3; seg++){
    #pragma unroll
    for (int q = 0; q < 4; q++){
      int kb = seg * 16 + q * 4;
      int s0 = __builtin_amdgcn_readlane(rowk, kb + 0);
      int s1 = __builtin_amdgcn_readlane(rowk, kb + 1);
      int s2 = __builtin_amdgcn_readlane(rowk, kb + 2);
      int s3 = __builtin_amdgcn_readlane(rowk, kb + 3);
      int sw0 = __builtin_amdgcn_readlane(wgtk, kb + 0);
      int sw1 = __builtin_amdgcn_readlane(wgtk, kb + 1);
      int sw2 = __builtin_amdgcn_readlane(wgtk, kb + 2);
      int sw3 = __builtin_amdgcn_readlane(wgtk, kb + 3);
      unsigned o0 = (((unsigned)s0) << 7) + lane4;
      unsigned o1 = (((unsigned)s1) << 7) + lane4;
      unsigned o2 = (((unsigned)s2) << 7) + lane4;
      unsigned o3 = (((unsigned)s3) << 7) + lane4;
      __half2 v0 = *(const __half2*)(vbase + o0);
      __half2 v1 = *(const __half2*)(vbase + o1);
      __half2 v2 = *(const __half2*)(vbase + o2);
      __half2 v3 = *(const __half2*)(vbase + o3);
      unsigned u0 = __builtin_amdgcn_perm((unsigned)sw0, (unsigned)sw0, selperm);
      unsigned u1 = __builtin_amdgcn_perm((unsigned)sw1, (unsigned)sw1, selperm);
      unsigned u2 = __builtin_amdgcn_perm((unsigned)sw2, (unsigned)sw2, selperm);
      unsigned u3 = __builtin_amdgcn_perm((unsigned)sw3, (unsigned)sw3, selperm);
      a0 = __hfma2(*(__half2*)&u0, v0, a0);
      a1 = __hfma2(*(__half2*)&u1, v1, a1);
      a2 = __hfma2(*(__half2*)&u2, v2, a2);
      a3 = __hfma2(*(__half2*)&u3, v3, a3);
    }
    float2 f0 = __half22float2(a0), f1 = __half22float2(a1);
    float2 f2 = __half22float2(a2), f3 = __half22float2(a3);
    fLo += (f0.x + f1.x) + (f2.x + f3.x);
    fHi += (f0.y + f1.y) + (f2.y + f3.y);
    a0 = a1 = a2 = a3 = hz;
  }

  // lanes i and i+32 hold the x-lo / x-hi halves of the same channel pair
  float sLo = fLo + __shfl_xor(fLo, 32);
  float sHi = fHi + __shfl_xor(fHi, 32);
  if (lane < 32){
    unsigned packed = ((unsigned)f2bf(sHi) << 16) | (unsigned)f2bf(sLo);
    *(unsigned*)(msout + (size_t)r * DIM + head * 64 + lane * 2) = packed;
  }
}

// depthwise 3x3x3 SAME conv per level segment + exact GELU; bf16 output.
// v5: float4 vectorized (thread = (row, channel-quad)).
__global__ void k_dwconv_gelu(const float* __restrict__ h, const float* __restrict__ dww,
                              const float* __restrict__ dwb, unsigned short* __restrict__ h2){
  int gid = blockIdx.x * blockDim.x + threadIdx.x;
  if (gid >= ROWS * 24) return;
  int c4 = gid % 24;
  int r = gid / 24;
  int c = c4 * 4;
  int b = (r >= NTOK) ? 1 : 0;
  int t = r - b * NTOK;
  int base, DL, i;
  if (t < L1START){ base = 0; DL = 24; i = t; }
  else if (t < L2START){ base = L1START; DL = 12; i = t - L1START; }
  else { base = L2START; DL = 6; i = t - L2START; }
  int dd, yy, xx;
  if (DL == 24){ dd = i / 576; int rem = i - dd*576; yy = rem / 24; xx = rem - yy*24; }
  else if (DL == 12){ dd = i / 144; int rem = i - dd*144; yy = rem / 12; xx = rem - yy*12; }
  else { dd = i / 36; int rem = i - dd*36; yy = rem / 6; xx = rem - yy*6; }
  float4 acc = {0.f, 0.f, 0.f, 0.f};
  #pragma unroll
  for (int kz = 0; kz < 3; kz++){
    int nd = dd + kz - 1; if (nd < 0 || nd >= DL) continue;
    #pragma unroll
    for (int ky = 0; ky < 3; ky++){
      int ny = yy + ky - 1; if (ny < 0 || ny >= DL) continue;
      #pragma unroll
      for (int kx = 0; kx < 3; kx++){
        int nx = xx + kx - 1; if (nx < 0 || nx >= DL) continue;
        int nt = base + (nd * DL + ny) * DL + nx;
        float4 hv = *(const float4*)(h + ((size_t)(b*NTOK + nt)) * HID + c);
        float4 wv = *(const float4*)(dww + (size_t)((kz*3 + ky)*3 + kx) * HID + c);
        acc.x += hv.x * wv.x; acc.y += hv.y * wv.y;
        acc.z += hv.z * wv.z; acc.w += hv.w * wv.w;
      }
    }
  }
  float4 bv = *(const float4*)(dwb + c);
  acc.x += bv.x; acc.y += bv.y; acc.z += bv.z; acc.w += bv.w;
  const float k = 0.70710678118654752440f;
  float g0 = 0.5f * acc.x * (1.f + erff(acc.x * k));
  float g1 = 0.5f * acc.y * (1.f + erff(acc.y * k));
  float g2 = 0.5f * acc.z * (1.f + erff(acc.z * k));
  float g3 = 0.5f * acc.w * (1.f + erff(acc.w * k));
  uint2 pk;
  pk.x = ((unsigned)f2bf(g1) << 16) | (unsigned)f2bf(g0);
  pk.y = ((unsigned)f2bf(g3) << 16) | (unsigned)f2bf(g2);
  *(uint2*)(h2 + (size_t)r * HID + c) = pk;
}

extern "C" void kernel_launch(void* const* d_in, const int* in_sizes, int n_in,
                              void* d_out, int out_size, void* d_ws, size_t ws_size,
                              hipStream_t stream){
  const float* query = (const float*)d_in[0];
  const float* feat  = (const float*)d_in[2];
  const float* qnw = (const float*)d_in[8],  *qnb = (const float*)d_in[9];
  const float* fnw = (const float*)d_in[10], *fnb = (const float*)d_in[11];
  const float* eqw = (const float*)d_in[12], *eqb = (const float*)d_in[13];
  const float* efw = (const float*)d_in[14], *efb = (const float*)d_in[15];
  const float* ffw = (const float*)d_in[16], *ffb = (const float*)d_in[17];
  const float* off_w = (const float*)d_in[18], *off_b = (const float*)d_in[19];
  const float* aw_w  = (const float*)d_in[20], *aw_b  = (const float*)d_in[21];
  const float* val_w = (const float*)d_in[22], *val_b = (const float*)d_in[23];
  const float* out_w = (const float*)d_in[24], *out_b = (const float*)d_in[25];
  const float* fc1_w = (const float*)d_in[26], *fc1_b = (const float*)d_in[27];
  const float* dw_w  = (const float*)d_in[28], *dw_b  = (const float*)d_in[29];
  const float* fc2_w = (const float*)d_in[30], *fc2_b = (const float*)d_in[31];
  float* out = (float*)d_out;

  // workspace layout (~171 MB with lifetime-disjoint aliasing)
  char* p = (char*)d_ws;
  float* qn             = (float*)p;          p += (size_t)ROWS*384*4;  // qn; later h2
  unsigned short* aq    = (unsigned short*)p; p += (size_t)MPAD*384*2;  // aq -> t
  unsigned short* af    = (unsigned short*)p; p += (size_t)MPAD*384*2;  // af -> msout
  __half* value_t       = (__half*)p;         p += (size_t)HEADS*VSLAB*2; // value; later h
  float* offaw          = (float*)p;          p += (size_t)ROWS*384*4;  // off+aw; later y1
  unsigned short* wt_val   = (unsigned short*)p; p += (size_t)384*384*2;
  unsigned short* wt_offaw = (unsigned short*)p; p += (size_t)384*384*2;
  unsigned short* wt_out   = (unsigned short*)p; p += (size_t)384*384*2;
  unsigned short* wt_fc1   = (unsigned short*)p; p += (size_t)128*384*2;
  unsigned short* wt_fc2   = (unsigned short*)p; p += (size_t)384*96*2;
  float* offaw_b           = (float*)p;          p += (size_t)384*4;
  // aliases (lifetime-disjoint)
  unsigned short* t_buf  = aq;                    // MPAD*384 bf16
  unsigned short* msout  = af;                    // MPAD*384 bf16
  float* y1              = offaw;                 // ROWS*384 f32 (offaw dead post-msdeform)
  float* h_buf           = (float*)value_t;       // ROWS*96 f32 (value dead post-msdeform)
  unsigned short* h2_buf = (unsigned short*)qn;   // MPAD*96 bf16 (qn dead post-out-GEMM)

  k_cvt_all<<<(528768 + 255)/256, 256, 0, stream>>>(val_w, off_w, aw_w, out_w, fc1_w, fc2_w,
                                                    off_b, aw_b,
                                                    wt_val, wt_offaw, wt_out, wt_fc1, wt_fc2,
                                                    offaw_b);

  int lnBlocks = ROWS / 4;
  k_ln_front<<<lnBlocks, 256, 0, stream>>>(query, feat, qnw, qnb, fnw, fnb,
                                           eqw, eqb, efw, efb, qn, aq, af);

  dim3 gN384(3, MPAD/128), gN128(1, MPAD/128);

  // value (f16, [head][row][64]) = af @ val_w + val_b
  k_gemm<2><<<gN384, 256, 0, stream>>>(af, wt_val, val_b, nullptr, value_t, ROWS, 384, 384);
  // off(0:216) + aw logits(256:328) = aq @ [off_w|aw_w] + [off_b|aw_b]
  k_gemm<0><<<gN384, 256, 0, stream>>>(aq, wt_offaw, offaw_b, nullptr, offaw, ROWS, 384, 384);
  // deformable sampling -> msout (bf16; af dead)
  k_msdeform<<<ROWS, 384, 0, stream>>>(value_t, offaw, msout);
  // y1 = msout @ out_w + out_b + qn   (offaw dead)
  k_gemm<0><<<gN384, 256, 0, stream>>>(msout, wt_out, out_b, qn, y1, ROWS, 384, 384);
  // t = LN(y1, ffn_norm)  (aq dead)
  k_ln<<<lnBlocks, 256, 0, stream>>>(y1, ffw, ffb, t_buf);
  // h = t @ fc1_w + fc1_b   (value dead)
  k_gemm<0><<<gN128, 256, 0, stream>>>(t_buf, wt_fc1, fc1_b, nullptr, h_buf, ROWS, 96, 384);
  // h2 = gelu(dwconv(h))    (qn dead)
  k_dwconv_gelu<<<(ROWS * 24 + 255)/256, 256, 0, stream>>>(h_buf, dw_w, dw_b, h2_buf);
  // out = h2 @ fc2_w + fc2_b + y1
  k_gemm<0><<<gN384, 256, 0, stream>>>(h2_buf, wt_fc2, fc2_b, y1, out, ROWS, 384, 96);
}